// Round 2
// baseline (280.483 us; speedup 1.0000x reference)
//
#include <hip/hip_runtime.h>
#include <hip/hip_bf16.h>

// Inputs may be fp32 or bf16 (harness ambiguous; round-1 NaN suggests fp32).
// A detect kernel sniffs W's byte pattern and sets a flag in ws; all kernels
// branch uniformly on it. Internal pipeline is always bf16 MFMA.

typedef unsigned short ushort_t;
typedef __attribute__((ext_vector_type(8))) short bf16x8;
typedef __attribute__((ext_vector_type(4))) float f32x4;

__device__ __forceinline__ float bf2f(ushort_t u) {
    unsigned v = ((unsigned)u) << 16;
    return __builtin_bit_cast(float, v);
}
__device__ __forceinline__ ushort_t f2bf(float x) {
    unsigned u = __builtin_bit_cast(unsigned, x);
    u += 0x7FFFu + ((u >> 16) & 1u);   // RNE; finite inputs
    return (ushort_t)(u >> 16);
}

// ---------------- kernel 0: dtype sniffing ----------------
// W ~ N(0, 0.0625^2): as true bf16, exponent field < 0x90 always.
// As fp32 bytes read as ushorts, low-half words have ~uniform exponent bits.
__global__ void detect_dtype(const ushort_t* __restrict__ W, int* __restrict__ flag) {
    if (threadIdx.x == 0) {
        int cnt = 0;
        for (int i = 0; i < 256; i++) {
            unsigned ex = (W[i] >> 7) & 0xFFu;
            if (ex >= 0x90u) cnt++;
        }
        *flag = (cnt > 8) ? 1 : 0;   // 1 -> inputs/outputs are fp32
    }
}

// ---------------- kernel 1: WT[c][k] = W[k][c], 512x512, bf16 out ----------------
__global__ __launch_bounds__(256) void transpose_w(const void* __restrict__ Wv,
                                                   ushort_t* __restrict__ WT,
                                                   const int* __restrict__ flag) {
    __shared__ ushort_t t[32][33];
    int isf = *flag;
    int bx = blockIdx.x & 15, by = blockIdx.x >> 4;
    int tx = threadIdx.x & 31, ty = threadIdx.x >> 5;   // ty 0..7
    if (isf) {
        const float* W32 = (const float*)Wv;
#pragma unroll
        for (int i = 0; i < 32; i += 8)
            t[ty + i][tx] = f2bf(W32[(by * 32 + ty + i) * 512 + bx * 32 + tx]);
    } else {
        const ushort_t* W16 = (const ushort_t*)Wv;
#pragma unroll
        for (int i = 0; i < 32; i += 8)
            t[ty + i][tx] = W16[(by * 32 + ty + i) * 512 + bx * 32 + tx];
    }
    __syncthreads();
#pragma unroll
    for (int i = 0; i < 32; i += 8)
        WT[(bx * 32 + ty + i) * 512 + by * 32 + tx] = t[tx][ty + i];
}

// ---------------- kernel 2: WhT[c][n] = sum_k W[k][c]*h[n][k], 512 x 4096 bf16 ----
__global__ __launch_bounds__(256) void gemm_whT(const ushort_t* __restrict__ WT,
                                                const void* __restrict__ hv,
                                                ushort_t* __restrict__ WhT,
                                                const int* __restrict__ flag) {
    __shared__ ushort_t Al[64][40];   // 80B rows: 16B-aligned, 2-way banks free
    __shared__ ushort_t Bl[64][40];
    int isf = *flag;
    int tid = threadIdx.x;
    int wave = tid >> 6, lane = tid & 63, quad = lane >> 4, nn = lane & 15;
    int mb = blockIdx.x & 7, nb = blockIdx.x >> 3;   // 8 m-tiles x 64 n-tiles
    int r = tid >> 2, part = tid & 3;                // staging: 64 rows x 4 segs
    const ushort_t* Ag = WT + (long)(mb * 64 + r) * 512 + part * 8;
    const ushort_t* Bg16 = (const ushort_t*)hv + (long)(nb * 64 + r) * 512 + part * 8;
    const float* Bg32 = (const float*)hv + (long)(nb * 64 + r) * 512 + part * 8;
    f32x4 acc[4] = {};
    for (int kb = 0; kb < 512; kb += 32) {
        __syncthreads();
        *(bf16x8*)&Al[r][part * 8] = *(const bf16x8*)(Ag + kb);
        if (isf) {
            float4 f0 = *(const float4*)(Bg32 + kb);
            float4 f1 = *(const float4*)(Bg32 + kb + 4);
            bf16x8 bvv;
            bvv[0] = (short)f2bf(f0.x); bvv[1] = (short)f2bf(f0.y);
            bvv[2] = (short)f2bf(f0.z); bvv[3] = (short)f2bf(f0.w);
            bvv[4] = (short)f2bf(f1.x); bvv[5] = (short)f2bf(f1.y);
            bvv[6] = (short)f2bf(f1.z); bvv[7] = (short)f2bf(f1.w);
            *(bf16x8*)&Bl[r][part * 8] = bvv;
        } else {
            *(bf16x8*)&Bl[r][part * 8] = *(const bf16x8*)(Bg16 + kb);
        }
        __syncthreads();
        bf16x8 af = *(const bf16x8*)&Al[wave * 16 + nn][quad * 8];
#pragma unroll
        for (int nt = 0; nt < 4; nt++) {
            bf16x8 bv = *(const bf16x8*)&Bl[nt * 16 + nn][quad * 8];
            acc[nt] = __builtin_amdgcn_mfma_f32_16x16x32_bf16(af, bv, acc[nt], 0, 0, 0);
        }
    }
    int row0 = mb * 64 + wave * 16 + quad * 4;
    int col0 = nb * 64 + nn;
#pragma unroll
    for (int nt = 0; nt < 4; nt++)
#pragma unroll
        for (int rr = 0; rr < 4; rr++)
            WhT[(long)(row0 + rr) * 4096 + col0 + nt * 16] = f2bf(acc[nt][rr]);
}

// ---------------- kernel 3: src/dst projections, [h][n] fp32 ----------------
__global__ __launch_bounds__(256) void src_dst(const ushort_t* __restrict__ WhT,
                                               const void* __restrict__ av,
                                               float* __restrict__ srcv,
                                               float* __restrict__ dstv,
                                               const int* __restrict__ flag) {
    __shared__ float as[128];
    int isf = *flag;
    int tid = threadIdx.x;
    if (tid < 128)
        as[tid] = isf ? ((const float*)av)[tid] : bf2f(((const ushort_t*)av)[tid]);
    __syncthreads();
    int nl = tid & 63, hq = tid >> 6;
    int n = blockIdx.x * 64 + nl;
#pragma unroll
    for (int hi = 0; hi < 2; hi++) {
        int hd = hq * 2 + hi;
        float s = 0.f, d = 0.f;
        for (int f = 0; f < 64; f++) {
            float v = bf2f(WhT[(long)(hd * 64 + f) * 4096 + n]);
            s += v * as[f];
            d += v * as[64 + f];
        }
        srcv[hd * 4096 + n] = s;
        dstv[hd * 4096 + n] = d;
    }
}

// ---------------- kernel 4: fused masked-softmax attention + P@V + ELU ----------------
__global__ __launch_bounds__(256) void gat_attn(const int* __restrict__ adj,
                                                const ushort_t* __restrict__ WhT,
                                                const float* __restrict__ srcv,
                                                const float* __restrict__ dstv,
                                                void* __restrict__ outv,
                                                const int* __restrict__ flag) {
    __shared__ ushort_t Pl[2][32][40];   // unnormalized weights, bf16
    __shared__ ushort_t Vl[128][40];     // WhT tile: 128 f rows x 32 j cols
    __shared__ float denoml[2][32];
    int isf = *flag;
    int tid = threadIdx.x;
    int wave = tid >> 6, lane = tid & 63, quad = lane >> 4, nn = lane & 15;
    int ib = blockIdx.x >> 2, hb = blockIdx.x & 3;
    int i0 = ib * 32;
    // P-gen role
    int hh = tid >> 7, tt = tid & 127;
    int pi = tt >> 2, jq = tt & 3;
    int head = hb * 2 + hh;
    float src_val = srcv[head * 4096 + i0 + pi];
    const int* adjRow = adj + (long)(i0 + pi) * 4096 + jq * 8;
    const float* dstRow = dstv + (long)head * 4096 + jq * 8;
    // V staging role
    int vr = tid >> 2, vpart = tid & 3;
    const ushort_t* Vg0 = WhT + (long)(hb * 128 + vr) * 4096 + vpart * 8;
    const ushort_t* Vg1 = WhT + (long)(hb * 128 + 64 + vr) * 4096 + vpart * 8;
    // MFMA role
    int strip = wave & 1, whead = wave >> 1;
    float dpart = 0.f;
    f32x4 acc[4] = {};
    for (int jb = 0; jb < 4096; jb += 32) {
        __syncthreads();
        bf16x8 pv;
#pragma unroll
        for (int q = 0; q < 2; q++) {
            int4 av = *(const int4*)(adjRow + jb + q * 4);
            float4 dv = *(const float4*)(dstRow + jb + q * 4);
            float e; ushort_t u;
            e = src_val + dv.x; e = fmaxf(e, 0.2f * e);
            u = f2bf(av.x > 0 ? __expf(e) : 0.f); pv[q * 4 + 0] = (short)u; dpart += bf2f(u);
            e = src_val + dv.y; e = fmaxf(e, 0.2f * e);
            u = f2bf(av.y > 0 ? __expf(e) : 0.f); pv[q * 4 + 1] = (short)u; dpart += bf2f(u);
            e = src_val + dv.z; e = fmaxf(e, 0.2f * e);
            u = f2bf(av.z > 0 ? __expf(e) : 0.f); pv[q * 4 + 2] = (short)u; dpart += bf2f(u);
            e = src_val + dv.w; e = fmaxf(e, 0.2f * e);
            u = f2bf(av.w > 0 ? __expf(e) : 0.f); pv[q * 4 + 3] = (short)u; dpart += bf2f(u);
        }
        *(bf16x8*)&Pl[hh][pi][jq * 8] = pv;
        *(bf16x8*)&Vl[vr][vpart * 8] = *(const bf16x8*)(Vg0 + jb);
        *(bf16x8*)&Vl[64 + vr][vpart * 8] = *(const bf16x8*)(Vg1 + jb);
        __syncthreads();
        bf16x8 af = *(const bf16x8*)&Pl[whead][strip * 16 + nn][quad * 8];
#pragma unroll
        for (int nt = 0; nt < 4; nt++) {
            bf16x8 bv = *(const bf16x8*)&Vl[whead * 64 + nt * 16 + nn][quad * 8];
            acc[nt] = __builtin_amdgcn_mfma_f32_16x16x32_bf16(af, bv, acc[nt], 0, 0, 0);
        }
    }
    float dsum = dpart;
    dsum += __shfl_xor(dsum, 1);
    dsum += __shfl_xor(dsum, 2);
    if ((tid & 3) == 0) denoml[hh][pi] = dsum;
    __syncthreads();
#pragma unroll
    for (int nt = 0; nt < 4; nt++) {
#pragma unroll
        for (int rr = 0; rr < 4; rr++) {
            int il = strip * 16 + quad * 4 + rr;
            float d = fmaxf(denoml[whead][il], 1e-30f);
            float v = acc[nt][rr] / d;
            v = v > 0.f ? v : __expf(v) - 1.f;
            long idx = (long)(i0 + il) * 512 + hb * 128 + whead * 64 + nt * 16 + nn;
            if (isf) ((float*)outv)[idx] = v;
            else     ((ushort_t*)outv)[idx] = f2bf(v);
        }
    }
}

extern "C" void kernel_launch(void* const* d_in, const int* in_sizes, int n_in,
                              void* d_out, int out_size, void* d_ws, size_t ws_size,
                              hipStream_t stream) {
    const void* h   = d_in[0];               // 4096 x 512 (fp32 or bf16)
    const int*  adj = (const int*)d_in[1];   // 4096 x 4096 int32
    const void* W   = d_in[2];               // 512 x 512
    const void* a   = d_in[3];               // 128

    char* ws = (char*)d_ws;
    ushort_t* WhT = (ushort_t*)ws;                              // 4 MB
    ushort_t* WT  = (ushort_t*)(ws + (4u << 20));               // 512 KB
    float* srcv   = (float*)(ws + (4u << 20) + (512u << 10));   // 128 KB
    float* dstv   = srcv + 8 * 4096;                            // 128 KB
    int* flag     = (int*)(ws + (5u << 20));

    detect_dtype<<<1, 64, 0, stream>>>((const ushort_t*)W, flag);
    transpose_w<<<256, 256, 0, stream>>>(W, WT, flag);
    gemm_whT<<<512, 256, 0, stream>>>(WT, h, WhT, flag);
    src_dst<<<64, 256, 0, stream>>>(WhT, a, srcv, dstv, flag);
    gat_attn<<<512, 256, 0, stream>>>(adj, WhT, srcv, dstv, d_out, flag);
}

// Round 3
// 197.250 us; speedup vs baseline: 1.4220x; 1.4220x over previous
//
#include <hip/hip_runtime.h>
#include <hip/hip_bf16.h>

// Inputs CONFIRMED fp32 (round-2: gat_attn WRITE_SIZE 8.2MB = 4096*512*4B).
// h fp32, adj int32, W fp32, a fp32; out fp32. Internal pipeline bf16 MFMA.

typedef unsigned short ushort_t;
typedef __attribute__((ext_vector_type(8))) short bf16x8;
typedef __attribute__((ext_vector_type(4))) float f32x4;

#define LOG2E 1.4426950408889634f

__device__ __forceinline__ ushort_t f2bf(float x) {
    unsigned u = __builtin_bit_cast(unsigned, x);
    u += 0x7FFFu + ((u >> 16) & 1u);   // RNE; finite inputs
    return (ushort_t)(u >> 16);
}

// ---------------- kernel 1: WT[c][k] = W[k][c], 512x512, fp32 in -> bf16 out ----------
__global__ __launch_bounds__(256) void transpose_w(const float* __restrict__ W,
                                                   ushort_t* __restrict__ WT) {
    __shared__ ushort_t t[32][33];
    int bx = blockIdx.x & 15, by = blockIdx.x >> 4;
    int tx = threadIdx.x & 31, ty = threadIdx.x >> 5;
#pragma unroll
    for (int i = 0; i < 32; i += 8)
        t[ty + i][tx] = f2bf(W[(by * 32 + ty + i) * 512 + bx * 32 + tx]);
    __syncthreads();
#pragma unroll
    for (int i = 0; i < 32; i += 8)
        WT[(bx * 32 + ty + i) * 512 + by * 32 + tx] = t[tx][ty + i];
}

// ---------------- kernel 2: WhT[c][n] = sum_k W[k][c]*h[n][k] + fused src/dst ---------
// Block (mb,nb): c-rows [mb*64,+64) = head mb's full 64 features -> can finish
// src/dst projections for its 64 columns in-block (no atomics).
__global__ __launch_bounds__(256) void gemm_whT(const ushort_t* __restrict__ WT,
                                                const float* __restrict__ h,
                                                const float* __restrict__ a,
                                                ushort_t* __restrict__ WhT,
                                                float* __restrict__ srcv,
                                                float* __restrict__ dstv) {
    __shared__ ushort_t Al[64][40];
    __shared__ ushort_t Bl[64][40];
    __shared__ float asrc[64], adst[64];
    __shared__ float sred[2][4][64];
    int tid = threadIdx.x;
    int wave = tid >> 6, lane = tid & 63, quad = lane >> 4, nn = lane & 15;
    int mb = blockIdx.x & 7, nb = blockIdx.x >> 3;
    if (tid < 64) {
        asrc[tid] = a[tid] * LOG2E;        // pre-scale: attn uses exp2
        adst[tid] = a[64 + tid] * LOG2E;
    }
    int r = tid >> 2, part = tid & 3;
    const ushort_t* Ag = WT + (long)(mb * 64 + r) * 512 + part * 8;
    const float* Bg = h + (long)(nb * 64 + r) * 512 + part * 8;
    f32x4 acc[4] = {};
    for (int kb = 0; kb < 512; kb += 32) {
        __syncthreads();
        *(bf16x8*)&Al[r][part * 8] = *(const bf16x8*)(Ag + kb);
        float4 f0 = *(const float4*)(Bg + kb);
        float4 f1 = *(const float4*)(Bg + kb + 4);
        bf16x8 bvv;
        bvv[0] = (short)f2bf(f0.x); bvv[1] = (short)f2bf(f0.y);
        bvv[2] = (short)f2bf(f0.z); bvv[3] = (short)f2bf(f0.w);
        bvv[4] = (short)f2bf(f1.x); bvv[5] = (short)f2bf(f1.y);
        bvv[6] = (short)f2bf(f1.z); bvv[7] = (short)f2bf(f1.w);
        *(bf16x8*)&Bl[r][part * 8] = bvv;
        __syncthreads();
        bf16x8 af = *(const bf16x8*)&Al[wave * 16 + nn][quad * 8];
#pragma unroll
        for (int nt = 0; nt < 4; nt++) {
            bf16x8 bv = *(const bf16x8*)&Bl[nt * 16 + nn][quad * 8];
            acc[nt] = __builtin_amdgcn_mfma_f32_16x16x32_bf16(af, bv, acc[nt], 0, 0, 0);
        }
    }
    int row0 = mb * 64 + wave * 16 + quad * 4;
    int col0 = nb * 64 + nn;
    int f0i = wave * 16 + quad * 4;
#pragma unroll
    for (int nt = 0; nt < 4; nt++) {
        float s = 0.f, d = 0.f;
#pragma unroll
        for (int rr = 0; rr < 4; rr++) {
            float v = acc[nt][rr];
            WhT[(long)(row0 + rr) * 4096 + col0 + nt * 16] = f2bf(v);
            s += v * asrc[f0i + rr];
            d += v * adst[f0i + rr];
        }
        s += __shfl_xor(s, 16); s += __shfl_xor(s, 32);
        d += __shfl_xor(d, 16); d += __shfl_xor(d, 32);
        if (quad == 0) { sred[0][wave][nt * 16 + nn] = s; sred[1][wave][nt * 16 + nn] = d; }
    }
    __syncthreads();
    if (tid < 64)
        srcv[(long)mb * 4096 + nb * 64 + tid] =
            sred[0][0][tid] + sred[0][1][tid] + sred[0][2][tid] + sred[0][3][tid];
    else if (tid < 128) {
        int c = tid - 64;
        dstv[(long)mb * 4096 + nb * 64 + c] =
            sred[1][0][c] + sred[1][1][c] + sred[1][2][c] + sred[1][3][c];
    }
}

// ---------------- kernel 3: fused masked-softmax attention + P@V + ELU ----------------
// 512 blocks x 512 threads (8 waves). j-tile 64, double-buffered LDS, 1 barrier/iter.
// Waves 0-3: jhalf 0, waves 4-7: jhalf 1 (split-j MFMA, combined at end).
__global__ __launch_bounds__(512, 4) void gat_attn(const int* __restrict__ adj,
                                                   const ushort_t* __restrict__ WhT,
                                                   const float* __restrict__ srcv,
                                                   const float* __restrict__ dstv,
                                                   float* __restrict__ out) {
    __shared__ __align__(16) ushort_t Vb[2][128][72];   // 36864 B
    __shared__ __align__(16) ushort_t Pb[2][2][32][72]; // 18432 B
    __shared__ float denoml[2][32];
    int tid = threadIdx.x;
    int wave = tid >> 6, lane = tid & 63, quad = lane >> 4, nn = lane & 15;
    int hb = blockIdx.x >> 7, ib = blockIdx.x & 127;   // hb-siblings -> same XCD
    int i0 = ib * 32;
    // gen role: thread -> (hh, pi, jo): 8 j-entries per iter
    int hh = tid >> 8, tt = tid & 255;
    int pi = tt >> 3, jo = tt & 7;
    int head = hb * 2 + hh;
    float srcV = srcv[(long)head * 4096 + i0 + pi];    // already log2e-scaled
    const int* adjP = adj + (long)(i0 + pi) * 4096 + jo * 8;
    const float* dstP = dstv + (long)head * 4096 + jo * 8;
    // V-stage role: rows vr, vr+64; col-seg vcs
    int vr = tid >> 3, vcs = tid & 7;
    const ushort_t* Vg0 = WhT + (long)(hb * 128 + vr) * 4096 + vcs * 8;
    const ushort_t* Vg1 = WhT + (long)(hb * 128 + 64 + vr) * 4096 + vcs * 8;
    // MFMA role
    int jhalf = wave >> 2, ws = wave & 3;
    int strip = ws & 1, whead = ws >> 1;

    int4 pa[2][2]; float4 pd[2][2]; bf16x8 pvv[2][2];
    {   // prologue: tile 0
        pa[0][0] = *(const int4*)(adjP);
        pa[0][1] = *(const int4*)(adjP + 4);
        pd[0][0] = *(const float4*)(dstP);
        pd[0][1] = *(const float4*)(dstP + 4);
        pvv[0][0] = *(const bf16x8*)(Vg0);
        pvv[0][1] = *(const bf16x8*)(Vg1);
    }
    f32x4 acc[4] = {};
    float dpart = 0.f;
#pragma unroll 2
    for (int k = 0; k < 64; k++) {
        int cb = k & 1;
        if (k < 63) {
            long jb = (long)(k + 1) * 64;
            pa[cb ^ 1][0] = *(const int4*)(adjP + jb);
            pa[cb ^ 1][1] = *(const int4*)(adjP + jb + 4);
            pd[cb ^ 1][0] = *(const float4*)(dstP + jb);
            pd[cb ^ 1][1] = *(const float4*)(dstP + jb + 4);
            pvv[cb ^ 1][0] = *(const bf16x8*)(Vg0 + jb);
            pvv[cb ^ 1][1] = *(const bf16x8*)(Vg1 + jb);
        }
        // gen tile k
        bf16x8 pv;
        float wsum = 0.f;
#pragma unroll
        for (int q = 0; q < 2; q++) {
            int4 av = pa[cb][q];
            float4 dv = pd[cb][q];
            float e, ww;
            e = srcV + dv.x; e = fmaxf(e, 0.2f * e);
            ww = __builtin_amdgcn_exp2f(av.x > 0 ? e : -10000.f);
            wsum += ww; pv[q * 4 + 0] = (short)f2bf(ww);
            e = srcV + dv.y; e = fmaxf(e, 0.2f * e);
            ww = __builtin_amdgcn_exp2f(av.y > 0 ? e : -10000.f);
            wsum += ww; pv[q * 4 + 1] = (short)f2bf(ww);
            e = srcV + dv.z; e = fmaxf(e, 0.2f * e);
            ww = __builtin_amdgcn_exp2f(av.z > 0 ? e : -10000.f);
            wsum += ww; pv[q * 4 + 2] = (short)f2bf(ww);
            e = srcV + dv.w; e = fmaxf(e, 0.2f * e);
            ww = __builtin_amdgcn_exp2f(av.w > 0 ? e : -10000.f);
            wsum += ww; pv[q * 4 + 3] = (short)f2bf(ww);
        }
        dpart += wsum;
        *(bf16x8*)&Pb[cb][hh][pi][jo * 8] = pv;
        *(bf16x8*)&Vb[cb][vr][vcs * 8] = pvv[cb][0];
        *(bf16x8*)&Vb[cb][64 + vr][vcs * 8] = pvv[cb][1];
        // mfma tile k-1 from other buffer
        if (k > 0) {
            int pb = cb ^ 1;
            bf16x8 af = *(const bf16x8*)&Pb[pb][whead][strip * 16 + nn][jhalf * 32 + quad * 8];
#pragma unroll
            for (int nt = 0; nt < 4; nt++) {
                bf16x8 bv = *(const bf16x8*)&Vb[pb][whead * 64 + nt * 16 + nn][jhalf * 32 + quad * 8];
                acc[nt] = __builtin_amdgcn_mfma_f32_16x16x32_bf16(af, bv, acc[nt], 0, 0, 0);
            }
        }
        __syncthreads();
    }
    {   // tail: mfma tile 63 (buffer 1)
        bf16x8 af = *(const bf16x8*)&Pb[1][whead][strip * 16 + nn][jhalf * 32 + quad * 8];
#pragma unroll
        for (int nt = 0; nt < 4; nt++) {
            bf16x8 bv = *(const bf16x8*)&Vb[1][whead * 64 + nt * 16 + nn][jhalf * 32 + quad * 8];
            acc[nt] = __builtin_amdgcn_mfma_f32_16x16x32_bf16(af, bv, acc[nt], 0, 0, 0);
        }
    }
    // denominator: reduce over jo (8 consecutive lanes)
    float dsum = dpart;
    dsum += __shfl_xor(dsum, 1);
    dsum += __shfl_xor(dsum, 2);
    dsum += __shfl_xor(dsum, 4);
    if ((tid & 7) == 0) denoml[hh][pi] = dsum;
    __syncthreads();
    // combine jhalf partials via LDS (overlay on Vb) and epilogue
    float (*cmb)[64][20] = reinterpret_cast<float (*)[64][20]>(&Vb[0][0][0]);
    if (jhalf == 1) {
#pragma unroll
        for (int nt = 0; nt < 4; nt++)
            *(f32x4*)&cmb[ws][lane][nt * 4] = acc[nt];
    }
    __syncthreads();
    if (jhalf == 0) {
#pragma unroll
        for (int nt = 0; nt < 4; nt++) {
            f32x4 o = acc[nt] + *(const f32x4*)&cmb[ws][lane][nt * 4];
#pragma unroll
            for (int rr = 0; rr < 4; rr++) {
                int il = strip * 16 + quad * 4 + rr;
                float d = fmaxf(denoml[whead][il], 1e-30f);
                float v = o[rr] / d;
                v = v > 0.f ? v : __expf(v) - 1.f;
                out[(long)(i0 + il) * 512 + hb * 128 + whead * 64 + nt * 16 + nn] = v;
            }
        }
    }
}

extern "C" void kernel_launch(void* const* d_in, const int* in_sizes, int n_in,
                              void* d_out, int out_size, void* d_ws, size_t ws_size,
                              hipStream_t stream) {
    const float* h   = (const float*)d_in[0];   // 4096 x 512 fp32
    const int*   adj = (const int*)d_in[1];     // 4096 x 4096 int32
    const float* W   = (const float*)d_in[2];   // 512 x 512 fp32
    const float* a   = (const float*)d_in[3];   // 128 fp32

    char* ws = (char*)d_ws;
    ushort_t* WhT = (ushort_t*)ws;                              // 4 MB
    ushort_t* WT  = (ushort_t*)(ws + (4u << 20));               // 512 KB
    float* srcv   = (float*)(ws + (4u << 20) + (512u << 10));   // 128 KB
    float* dstv   = srcv + 8 * 4096;                            // 128 KB

    transpose_w<<<256, 256, 0, stream>>>(W, WT);
    gemm_whT<<<512, 256, 0, stream>>>(WT, h, a, WhT, srcv, dstv);
    gat_attn<<<512, 512, 0, stream>>>(adj, WhT, srcv, dstv, (float*)d_out);
}